// Round 5
// baseline (444.507 us; speedup 1.0000x reference)
//
#include <hip/hip_runtime.h>
#include <hip/hip_bf16.h>

// Downsample: ternary-quantized conv3x3 stride2 pad1, NCHW.
// x:(32,384,64,64) f32, w:(384,384,3,3) f32, bias:(384,) f32 -> out:(32,384,32,32) f32
// Implicit GEMM: M=32768 (n,oh,ow), N=384 (o), K=3456 ((kh,kw,c)), bf16 MFMA.
// Round 8: R0 geometry x R3 deep cover.
//   - BM=128 x BN=128, 256 thr / 4 waves, grid (256,3) -> 768 blocks; the 3
//     o-tiles sharing an X panel land on the SAME XCD (ids differ by 256).
//   - R0's VERIFIED conflict-free mappings (16x16x32 MFMA, quad-based octet
//     swizzle) for staging, ds_read, and epilogue -- byte-identical.
//   - Deep cover: lW dbuf + lX tribuf (80 KiB -> 2 blocks/CU); W(t+1) and
//     X(t+2) issued at top of step t; ONE EDGE_V(4) per step (never 0).
//   - 2 blocks/CU = two independent barrier domains per CU: inter-block
//     overlap fills barrier/latency bubbles (the m114 effect R0 exploited,
//     which every 1-block/CU redesign lost).
// Deterministic: no atomics anywhere.

#define CIN   384
#define HIN   64
#define WIN   64
#define OHW   32
#define KDIM  3456          // 9*384
#define NWELT 1327104       // 384*384*9
#define MDIM  32768         // 32*32*32
#define NT    54            // K-steps of 64; t = khkw*6 + cc  (k = t*64)

using bf16 = __hip_bfloat16;
typedef __attribute__((ext_vector_type(8))) short short8;   // MFMA A/B frag (8 bf16)
typedef __attribute__((ext_vector_type(4))) float floatx4;  // MFMA C/D frag
typedef __attribute__((ext_vector_type(2))) unsigned short ushort2v;

#define AS1 __attribute__((address_space(1)))
#define AS3 __attribute__((address_space(3)))
#define DMA16(g, l) __builtin_amdgcn_global_load_lds((const AS1 void*)(g), (AS3 void*)(l), 16, 0, 0)

// step edge: counted vmem wait + raw barrier + sched fence (the ONLY fence).
#define EDGE_V(N) do { \
    asm volatile("s_waitcnt vmcnt(" #N ")" ::: "memory"); \
    __builtin_amdgcn_s_barrier(); \
    __builtin_amdgcn_sched_barrier(0); \
} while (0)

// ws layout (floats): [0]=alpha, [1]=thr, [2..64)=62 partials; f[16..20) is
// REUSED as a 16B zero region (written by absum_final AFTER consuming partials).
// bytes [256, 256+100663296): x_nhwc bf16 [32][64][64][384]
// bytes [256+100663296, +2654208): Wq bf16 [384][3456] (k=(kh*3+kw)*384+c)
#define NPART  62
#define ZG_F   16
#define XN_OFF 256
#define WQ_OFF (256 + 100663296)

// ---- Stage 1: fixed-slot partial sums of |w| (no atomics -> deterministic) ----
__global__ void absum_part(const float* __restrict__ w, float* __restrict__ ws) {
    const float4* w4 = (const float4*)w;
    float s = 0.f;
    for (int i = blockIdx.x * 256 + threadIdx.x; i < NWELT / 4; i += NPART * 256) {
        float4 v = w4[i];
        s += fabsf(v.x) + fabsf(v.y) + fabsf(v.z) + fabsf(v.w);
    }
    for (int off = 32; off; off >>= 1) s += __shfl_down(s, off, 64);
    __shared__ float red[4];
    if ((threadIdx.x & 63) == 0) red[threadIdx.x >> 6] = s;
    __syncthreads();
    if (threadIdx.x == 0) ws[2 + blockIdx.x] = red[0] + red[1] + red[2] + red[3];
}

// ---- Stage 2: fixed-order final reduction; also zero the DMA guard region ----
__global__ void absum_final(float* __restrict__ ws) {
    if (threadIdx.x == 0) {
        float s = 0.f;
        for (int i = 0; i < NPART; ++i) s += ws[2 + i];
        float alpha = s * (1.0f / NWELT);
        ws[0] = alpha;
        ws[1] = 1e-3f * alpha;
        ws[ZG_F + 0] = 0.f; ws[ZG_F + 1] = 0.f;   // 16B zero guard (partials dead now)
        ws[ZG_F + 2] = 0.f; ws[ZG_F + 3] = 0.f;
    }
}

// ---- Ternary quantize, output-indexed (coalesced 2B writes; reads L2/L3-hot) ----
__global__ void quant_kernel(const float* __restrict__ w, const float* __restrict__ ws,
                             bf16* __restrict__ wq) {
    int j = blockIdx.x * 256 + threadIdx.x;   // j = o*3456 + (kh*3+kw)*384 + c
    if (j >= NWELT) return;
    float thr = ws[1];
    int o = j / KDIM;
    int rmd = j - o * KDIM;
    int khkw = rmd / 384;
    int c = rmd - khkw * 384;
    float v = w[((o * 384 + c) * 9) + khkw];
    float q = (v > thr) ? 1.f : ((v < -thr) ? -1.f : 0.f);
    wq[j] = __float2bfloat16(q);
}

// ---- NCHW f32 -> NHWC bf16. Block: 64c x 64w for one (n,h). grid=(2048, 6). ----
__global__ void nhwc_kernel(const float* __restrict__ x, bf16* __restrict__ xn) {
    int nh = blockIdx.x;
    int n = nh >> 6, h = nh & 63;
    int c0 = blockIdx.y * 64;
    __shared__ bf16 tile[64][66];   // stride 66: column reads ~conflict-free (33c banks)
    const float* src = x + ((n * CIN + c0) * HIN + h) * WIN;  // c-row stride 4096 floats
    for (int i = 0; i < 4; ++i) {
        int s = threadIdx.x + i * 256;     // [0,1024): 64c x 16 float4
        int cl = s >> 4, w4 = (s & 15) * 4;
        float4 v = *(const float4*)(src + cl * 4096 + w4);
        bf16 t0[2], t1[2];
        t0[0] = __float2bfloat16(v.x); t0[1] = __float2bfloat16(v.y);
        t1[0] = __float2bfloat16(v.z); t1[1] = __float2bfloat16(v.w);
        *(ushort2v*)&tile[cl][w4]     = *(ushort2v*)t0;   // 4B aligned
        *(ushort2v*)&tile[cl][w4 + 2] = *(ushort2v*)t1;
    }
    __syncthreads();
    bf16* dst = xn + ((size_t)(n * HIN + h) * WIN) * CIN + c0;
    for (int i = 0; i < 2; ++i) {
        int q = threadIdx.x + i * 256;     // [0,512): 64w x 8 c-octets
        int wc = q >> 3, c8 = (q & 7) * 8;
        bf16 tmp[8];
        #pragma unroll
        for (int j = 0; j < 8; ++j) tmp[j] = tile[c8 + j][wc];
        *(short8*)(dst + (size_t)wc * CIN + c8) = *(short8*)tmp;
    }
}

// ---- GEMM: D[o][m] = sum_k Wq[o][k] * X[m][k]. A=Wq, B=X. ----
// BM=128 (m), BN=128 (o), BK=64. 4 waves, each 64x64 (4x4 frags of 16x16x32).
// LDS layout (per buffer, 128 rows x 64 k-elements, unpadded 128B rows):
//   slot(r, oct) at bytes r*128 + oct*16 holds global octet (oct ^ (r&7)) of row r.
// DMA coverage: call (wv,i) covers slots (wv*4+i)*64 + lane; lane's global octet
//   g = (lane&7) ^ (lane>>3), row r = (wv*4+i)*8 + (lane>>3).
// ds_read side: octet og of row r lives at slot og ^ (r&7); with r = ..+(lane&15)
//   this folds to slot = (ks*4 + quad) ^ (lane&7) -> measured conflict-free.
// Ledger (per wave): enter t with [4 X(t+1)]; issue 4 W(t+1) + 4 X(t+2) -> 12;
//   EDGE_V(4) retires 4 X(t+1) + 4 W(t+1). One barrier per step; all frag
//   reads are consumed by MFMAs pinned before sched_barrier(0), so post-
//   barrier overwrites of lW[(t+1)&1] / lX[(t+2)%3] are WAR-safe.
#define BM  128
#define BN  128

__global__ __launch_bounds__(256, 2) void conv_gemm(const bf16* __restrict__ xn,
                                                    const bf16* __restrict__ wq,
                                                    const float* __restrict__ ws,
                                                    const float* __restrict__ bias,
                                                    float* __restrict__ out,
                                                    const bf16* __restrict__ zg) {
    __shared__ __align__(16) bf16 lW[2][BN * 64];    // 32 KiB
    __shared__ __align__(16) bf16 lX[3][BM * 64];    // 48 KiB  (total 80 KiB -> 2/CU)
    const int m_base = blockIdx.x * BM;              // 256 m-tiles
    const int o_base = blockIdx.y * BN;              // 3 o-tiles
    const int tid = threadIdx.x;
    const int lane = tid & 63;
    const int wv = tid >> 6;                         // 0..3
    const int wo = (wv & 1) * 64;
    const int wm = (wv >> 1) * 64;
    const int g = (lane & 7) ^ (lane >> 3);          // pre-swizzled global octet

    // ---- staging descriptors (R0-verified layout) ----
    const bf16* pw[4];
    const bf16* pxn[4];
    int oh2[4], ow2[4], wLoff[4], xLoff[4];
    #pragma unroll
    for (int i = 0; i < 4; ++i) {
        int rr = (wv * 4 + i) * 8;                   // row-group base [0,128)
        wLoff[i] = rr * 64;
        xLoff[i] = rr * 64;
        pw[i] = wq + (size_t)(o_base + rr + (lane >> 3)) * KDIM + g * 8;
        int m = m_base + rr + (lane >> 3);
        int n = m >> 10, oh = (m >> 5) & 31, ow = m & 31;
        pxn[i] = xn + (size_t)n * (HIN * WIN * CIN) + g * 8;
        oh2[i] = 2 * oh - 1;
        ow2[i] = 2 * ow - 1;
    }

    const int l15 = lane & 15, quad = lane >> 4, l7 = lane & 7;

    floatx4 acc[4][4];
    #pragma unroll
    for (int i = 0; i < 4; ++i)
        #pragma unroll
        for (int j = 0; j < 4; ++j)
            acc[i][j] = (floatx4){0.f, 0.f, 0.f, 0.f};

    // ---- prologue: X(0)->lX[0], W(0)->lW[0], X(1)->lX[1]; leave 4 X(1) in flight ----
    {
        #pragma unroll
        for (int i = 0; i < 4; ++i) {                // X(0): khkw=0 (kh=kw=0), cc=0
            int ih = oh2[i], iw = ow2[i];
            const bf16* p = (ih >= 0 && iw >= 0) ? pxn[i] + (ih * WIN + iw) * CIN : zg;
            DMA16(p, &lX[0][xLoff[i]]);
        }
        #pragma unroll
        for (int i = 0; i < 4; ++i)                  // W(0)
            DMA16(pw[i], &lW[0][wLoff[i]]);
        #pragma unroll
        for (int i = 0; i < 4; ++i) {                // X(1): khkw=0, cc=1
            int ih = oh2[i], iw = ow2[i];
            const bf16* p = (ih >= 0 && iw >= 0) ? pxn[i] + (ih * WIN + iw) * CIN + 64 : zg;
            DMA16(p, &lX[1][xLoff[i]]);
        }
        EDGE_V(4);   // X(0)+W(0) landed; [4 X(1)] in flight -> steady-state invariant
    }

    for (int t = 0; t < NT - 1; ++t) {               // t = 0..52
        const bf16* lWc = lW[t & 1];
        const bf16* lXc = lX[t % 3];
        bf16* lWn = lW[(t + 1) & 1];
        bf16* lXn2 = lX[(t + 2) % 3];
        const int kW = (t + 1) * 64;                 // W k-offset for step t+1 (linear)
        const int s2 = t + 2;                        // X staging step
        const int khkw2 = s2 / 6, cc2 = s2 - khkw2 * 6;
        const int kh2 = khkw2 / 3, kw2 = khkw2 - kh2 * 3;

        // ---- frag reads, both ks (verified conflict-free pattern) ----
        short8 af[2][4], bfr[2][4];
        #pragma unroll
        for (int ks = 0; ks < 2; ++ks) {
            const int oct = ((ks * 4 + quad) ^ l7) * 8;
            #pragma unroll
            for (int i = 0; i < 4; ++i)
                af[ks][i] = *(const short8*)(lWc + (wo + i * 16 + l15) * 64 + oct);
            #pragma unroll
            for (int j = 0; j < 4; ++j)
                bfr[ks][j] = *(const short8*)(lXc + (wm + j * 16 + l15) * 64 + oct);
        }

        // ---- staging: W(t+1) one-step cover (L2-hot), X(t+2) two-step (HBM) ----
        #pragma unroll
        for (int i = 0; i < 4; ++i)
            DMA16(pw[i] + kW, lWn + wLoff[i]);
        #pragma unroll
        for (int i = 0; i < 4; ++i) {
            int ih = oh2[i] + kh2, iw = ow2[i] + kw2;
            bool valid = (ih >= 0) & (iw >= 0) & (s2 < NT);
            const bf16* p = valid ? pxn[i] + (ih * WIN + iw) * CIN + cc2 * 64 : zg;
            DMA16(p, lXn2 + xLoff[i]);
        }

        // ---- MFMA: 2 ks x 4x4 (order identical to R0 -> bitwise-same acc) ----
        __builtin_amdgcn_s_setprio(1);
        #pragma unroll
        for (int ks = 0; ks < 2; ++ks)
            #pragma unroll
            for (int i = 0; i < 4; ++i)
                #pragma unroll
                for (int j = 0; j < 4; ++j)
                    acc[i][j] = __builtin_amdgcn_mfma_f32_16x16x32_bf16(
                        af[ks][i], bfr[ks][j], acc[i][j], 0, 0, 0);
        __builtin_amdgcn_s_setprio(0);

        EDGE_V(4);   // retire 4 X(t+1) + 4 W(t+1); keep 4 X(t+2) in flight
    }

    // ---- peeled tail (t = 53): everything resident; no staging, no barrier ----
    {
        const bf16* lWc = lW[1];
        const bf16* lXc = lX[53 % 3];    // lX[2]
        short8 af[2][4], bfr[2][4];
        #pragma unroll
        for (int ks = 0; ks < 2; ++ks) {
            const int oct = ((ks * 4 + quad) ^ l7) * 8;
            #pragma unroll
            for (int i = 0; i < 4; ++i)
                af[ks][i] = *(const short8*)(lWc + (wo + i * 16 + l15) * 64 + oct);
            #pragma unroll
            for (int j = 0; j < 4; ++j)
                bfr[ks][j] = *(const short8*)(lXc + (wm + j * 16 + l15) * 64 + oct);
        }
        __builtin_amdgcn_s_setprio(1);
        #pragma unroll
        for (int ks = 0; ks < 2; ++ks)
            #pragma unroll
            for (int i = 0; i < 4; ++i)
                #pragma unroll
                for (int j = 0; j < 4; ++j)
                    acc[i][j] = __builtin_amdgcn_mfma_f32_16x16x32_bf16(
                        af[ks][i], bfr[ks][j], acc[i][j], 0, 0, 0);
        __builtin_amdgcn_s_setprio(0);
    }

    // ---- epilogue: D row=(lane>>4)*4+reg = o, col=lane&15 = m -> coalesced along ow ----
    float alpha = ws[0];
    #pragma unroll
    for (int i = 0; i < 4; ++i) {
        #pragma unroll
        for (int j = 0; j < 4; ++j) {
            int mm = m_base + wm + j * 16 + l15;
            int n = mm >> 10, oh = (mm >> 5) & 31, ow = mm & 31;
            #pragma unroll
            for (int r = 0; r < 4; ++r) {
                int o = o_base + wo + i * 16 + quad * 4 + r;
                out[((n * 384 + o) * OHW + oh) * OHW + ow] = alpha * acc[i][j][r] + bias[o];
            }
        }
    }
}

extern "C" void kernel_launch(void* const* d_in, const int* in_sizes, int n_in,
                              void* d_out, int out_size, void* d_ws, size_t ws_size,
                              hipStream_t stream) {
    (void)in_sizes; (void)n_in; (void)out_size; (void)ws_size;
    const float* x    = (const float*)d_in[0];
    const float* w    = (const float*)d_in[1];
    const float* bias = (const float*)d_in[2];
    float* out = (float*)d_out;
    float* wsf = (float*)d_ws;
    bf16* xn = (bf16*)((char*)d_ws + XN_OFF);
    bf16* wq = (bf16*)((char*)d_ws + WQ_OFF);
    const bf16* zg = (const bf16*)(wsf + ZG_F);

    absum_part<<<NPART, 256, 0, stream>>>(w, wsf);
    absum_final<<<1, 64, 0, stream>>>(wsf);
    quant_kernel<<<(NWELT + 255) / 256, 256, 0, stream>>>(w, wsf, wq);
    nhwc_kernel<<<dim3(2048, 6), 256, 0, stream>>>(x, xn);
    conv_gemm<<<dim3(MDIM / BM, 384 / BN), 256, 0, stream>>>(xn, wq, wsf, bias, out, zg);
}